// Round 18
// baseline (135.523 us; speedup 1.0000x reference)
//
#include <hip/hip_runtime.h>

typedef __attribute__((ext_vector_type(8))) short short8;
typedef __attribute__((ext_vector_type(4))) float f32x4;
typedef __attribute__((ext_vector_type(4))) unsigned int u32x4;

// ---- LDS layout: exactly 40 KB ----
#define K_OFF   0              // 64 rows x 128 B (K tile, bf16, swizzled)
#define KR_OFF  8192           // 128 slots x 128 B (k_r circular band)
#define V_OFF   24576          // 64 d-rows x 128 B (V transposed)
#define P_OFF   32768          // 64 rows x 128 B (P bf16, swizzled)
#define SMEM_SZ 40960

union S8U { u32x4 u; short8 s; };

// Manual RNE bf16 pack (PROVEN r3-r17). NOT pk2-via-cvt (r6 fail: pair order).
__device__ __forceinline__ unsigned short f2bf(float x) {
  unsigned u = __float_as_uint(x);
  return (unsigned short)((u + 0x7FFFu + ((u >> 16) & 1u)) >> 16);
}
__device__ __forceinline__ unsigned pk2(float a, float b) {
  return (unsigned)f2bf(a) | ((unsigned)f2bf(b) << 16);
}

// seg_mat dtype probe: flags[0] = 0:int32  1:f32  2:byte/bool
__global__ void detect_kernel(const unsigned* __restrict__ segw, int* __restrict__ flags) {
  if (threadIdx.x >= 64) return;
  int a = 0, c = 0;
  for (int i = threadIdx.x; i < 1024; i += 64) {
    unsigned v = segw[i];
    if (v > 1u) a++;
    if (v != 0u && v != 0x3F800000u) c++;
  }
  for (int m = 1; m < 64; m <<= 1) { a += __shfl_xor(a, m); c += __shfl_xor(c, m); }
  if (threadIdx.x == 0) flags[0] = (a == 0) ? 0 : ((c == 0) ? 1 : 2);
}

// pb[(((q*4+b)*16 + t)*64 + lan16*4 + c] = (mask!=0)<<1 | (seg!=0)
__global__ __launch_bounds__(256) void
pack_kernel(const float* __restrict__ attn_mask, const void* __restrict__ seg_mat,
            const int* __restrict__ flags, unsigned char* __restrict__ pb) {
  const int segmode = flags[0];
  const int idx = blockIdx.x * 256 + threadIdx.x;
  const int q = idx >> 10, j = idx & 1023;
  const int tt = j >> 6, cc = (j >> 4) & 3, ll = j & 15;
  const float4 m4 = *(const float4*)(attn_mask + (size_t)idx * 4);
  unsigned sm[4];
  if (segmode == 2) {
    const unsigned char* sp = (const unsigned char*)seg_mat + (size_t)idx * 4;
    sm[0] = sp[0]; sm[1] = sp[1]; sm[2] = sp[2]; sm[3] = sp[3];
  } else {
    const unsigned* sp = (const unsigned*)seg_mat + (size_t)idx * 4;
    sm[0] = sp[0]; sm[1] = sp[1]; sm[2] = sp[2]; sm[3] = sp[3];
  }
  const float mm[4] = {m4.x, m4.y, m4.z, m4.w};
#pragma unroll
  for (int b = 0; b < 4; b++)
    pb[(((size_t)q * 4 + b) * 16 + tt) * 64 + ll * 4 + cc] =
        (unsigned char)(((mm[b] != 0.f) ? 2u : 0u) | ((sm[b] != 0u) ? 1u : 0u));
}

// One-time f32->bf16 image prepack in exact main-kernel LDS byte layout (PROVEN r9).
__global__ __launch_bounds__(256) void
prepack_kernel(const float* __restrict__ k_head_h, const float* __restrict__ v_head_h,
               const float* __restrict__ k_head_r,
               unsigned char* __restrict__ kimg, unsigned char* __restrict__ vimg,
               unsigned char* __restrict__ krimg) {
  __shared__ float vst[64 * 68];
  const int blk = blockIdx.x, tid = threadIdx.x;
  if (blk < 1024) {
    const int bn = blk >> 4, t = blk & 15;
    const int jj = tid >> 2, dblk = tid & 3;
    const float* kp = k_head_h + (size_t)(t * 64 + jj) * 4096 + bn * 64 + dblk * 16;
    float4 a0 = *(const float4*)(kp);
    float4 a1 = *(const float4*)(kp + 4);
    float4 a2 = *(const float4*)(kp + 8);
    float4 a3 = *(const float4*)(kp + 12);
    const unsigned swJ = (unsigned)((jj & 7) << 4);
    u32x4 w0 = (u32x4){pk2(a0.x, a0.y), pk2(a0.z, a0.w), pk2(a1.x, a1.y), pk2(a1.z, a1.w)};
    u32x4 w1 = (u32x4){pk2(a2.x, a2.y), pk2(a2.z, a2.w), pk2(a3.x, a3.y), pk2(a3.z, a3.w)};
    unsigned char* dst = kimg + (size_t)blk * 8192 + jj * 128;
    *(u32x4*)(dst + ((unsigned)(dblk * 32) ^ swJ)) = w0;
    *(u32x4*)(dst + ((unsigned)(dblk * 32 + 16) ^ swJ)) = w1;
  } else if (blk < 2048) {
    const int b2 = blk - 1024;
    const int bn = b2 >> 4, t = b2 & 15;
    const int jj = tid >> 2, dblk = tid & 3;
    const float* vp = v_head_h + (size_t)(t * 64 + jj) * 4096 + bn * 64 + dblk * 16;
    float4 a0 = *(const float4*)(vp);
    float4 a1 = *(const float4*)(vp + 4);
    float4 a2 = *(const float4*)(vp + 8);
    float4 a3 = *(const float4*)(vp + 12);
    float* vr = &vst[jj * 68 + dblk * 16];
    *(float4*)(vr) = a0; *(float4*)(vr + 4) = a1;
    *(float4*)(vr + 8) = a2; *(float4*)(vr + 12) = a3;
    __syncthreads();
    const int d2 = tid & 31, jc = tid >> 5;
    float2 e[8];
#pragma unroll
    for (int q8 = 0; q8 < 8; q8++)
      e[q8] = *(const float2*)(&vst[(jc * 8 + q8) * 68 + 2 * d2]);
    u32x4 wA = (u32x4){pk2(e[0].x, e[1].x), pk2(e[2].x, e[3].x),
                       pk2(e[4].x, e[5].x), pk2(e[6].x, e[7].x)};
    u32x4 wB = (u32x4){pk2(e[0].y, e[1].y), pk2(e[2].y, e[3].y),
                       pk2(e[4].y, e[5].y), pk2(e[6].y, e[7].y)};
    const int dA = 2 * d2, dB = dA + 1;
    unsigned char* dst = vimg + (size_t)b2 * 8192;
    *(u32x4*)(dst + dA * 128 + ((unsigned)(jc * 16) ^ ((unsigned)(dA & 7) << 4))) = wA;
    *(u32x4*)(dst + dB * 128 + ((unsigned)(jc * 16) ^ ((unsigned)(dB & 7) << 4))) = wB;
  } else {
    const int b3 = blk - 2048;
    const int bn = b3 >> 4, rseg = b3 & 15;
    const int r = rseg * 128 + (tid >> 1), dh = tid & 1;
    const unsigned sw = (unsigned)((r & 7) << 4);
    const float* rp = k_head_r + (size_t)r * 4096 + bn * 64 + dh * 32;
    unsigned char* dst = krimg + ((size_t)bn * 2048 + r) * 128;
#pragma unroll
    for (int h = 0; h < 4; h++) {
      float4 b0 = *(const float4*)(rp + h * 8);
      float4 b1 = *(const float4*)(rp + h * 8 + 4);
      u32x4 ww = (u32x4){pk2(b0.x, b0.y), pk2(b0.z, b0.w), pk2(b1.x, b1.y), pk2(b1.z, b1.w)};
      *(u32x4*)(dst + ((unsigned)(dh * 64 + h * 16) ^ sw)) = ww;
    }
  }
}

#define MFMA16(A, B, C) __builtin_amdgcn_mfma_f32_16x16x32_bf16((A), (B), (C), 0, 0, 0)

// MODE: 0 = naive, 1 = pb, 2 = pb + bf16 images
template<int MODE>
__global__ __launch_bounds__(256, 3) void
attn_mfma(const float* __restrict__ q_head, const float* __restrict__ k_head_h,
          const float* __restrict__ v_head_h, const float* __restrict__ k_head_r,
          const float* __restrict__ seg_embed, const float* __restrict__ r_w_bias,
          const float* __restrict__ r_r_bias, const float* __restrict__ r_s_bias,
          const float* __restrict__ attn_mask, const void* __restrict__ seg_mat,
          const unsigned char* __restrict__ pb,
          const unsigned char* __restrict__ kimg, const unsigned char* __restrict__ vimg,
          const unsigned char* __restrict__ krimg,
          float* __restrict__ out, const int* __restrict__ flags) {
  __shared__ __attribute__((aligned(128))) unsigned char smem[SMEM_SZ];
  const int segmode = flags[0];
  const int tid = threadIdx.x;
  const int w = tid >> 6, l = tid & 63;
  const int g = l >> 4, lan16 = l & 15;
  const int orig = blockIdx.x;
  const int wg = ((orig & 7) << 7) | (orig >> 3);
  const int i0 = (wg & 15) << 6;
  const int bn = wg >> 4, b = bn >> 4, n = bn & 15;
  const int rbase0 = 961 - i0;

  const int jj = tid >> 2, dblk = tid & 3;
  const int d2 = tid & 31, jc = tid >> 5;
  const int prr = tid >> 1, pdh = tid & 1;

  // ---- prologue: stage tile 0 ----
  if constexpr (MODE == 2) {
    const unsigned char* kt = kimg + (size_t)(bn * 16) * 8192;
    *(u32x4*)(smem + K_OFF + tid * 32)      = *(const u32x4*)(kt + tid * 32);
    *(u32x4*)(smem + K_OFF + tid * 32 + 16) = *(const u32x4*)(kt + tid * 32 + 16);
    const unsigned char* vt = vimg + (size_t)(bn * 16) * 8192;
    *(u32x4*)(smem + V_OFF + tid * 32)      = *(const u32x4*)(vt + tid * 32);
    *(u32x4*)(smem + V_OFF + tid * 32 + 16) = *(const u32x4*)(vt + tid * 32 + 16);
    const int r = rbase0 + prr;
    const unsigned char* rs = krimg + ((size_t)bn * 2048 + r) * 128 + pdh * 64;
    unsigned char* rd = smem + KR_OFF + (r & 127) * 128 + pdh * 64;   // slot&7==r&7: identity
    *(u32x4*)(rd)      = *(const u32x4*)(rs);
    *(u32x4*)(rd + 16) = *(const u32x4*)(rs + 16);
    *(u32x4*)(rd + 32) = *(const u32x4*)(rs + 32);
    *(u32x4*)(rd + 48) = *(const u32x4*)(rs + 48);
  } else {
    const float* kp = k_head_h + (size_t)jj * 4096 + bn * 64 + dblk * 16;
    float4 a0 = *(const float4*)(kp);
    float4 a1 = *(const float4*)(kp + 4);
    float4 a2 = *(const float4*)(kp + 8);
    float4 a3 = *(const float4*)(kp + 12);
    const unsigned swJ = (unsigned)((jj & 7) << 4);
    u32x4 w0 = (u32x4){pk2(a0.x, a0.y), pk2(a0.z, a0.w), pk2(a1.x, a1.y), pk2(a1.z, a1.w)};
    u32x4 w1 = (u32x4){pk2(a2.x, a2.y), pk2(a2.z, a2.w), pk2(a3.x, a3.y), pk2(a3.z, a3.w)};
    *(u32x4*)(smem + K_OFF + jj * 128 + ((unsigned)(dblk * 32) ^ swJ)) = w0;
    *(u32x4*)(smem + K_OFF + jj * 128 + ((unsigned)(dblk * 32 + 16) ^ swJ)) = w1;

    const float* vp = v_head_h + (size_t)(jc * 8) * 4096 + bn * 64 + 2 * d2;
    float2 e[8];
#pragma unroll
    for (int q8 = 0; q8 < 8; q8++) e[q8] = *(const float2*)(vp + (size_t)q8 * 4096);
    u32x4 wA = (u32x4){pk2(e[0].x, e[1].x), pk2(e[2].x, e[3].x),
                       pk2(e[4].x, e[5].x), pk2(e[6].x, e[7].x)};
    u32x4 wB = (u32x4){pk2(e[0].y, e[1].y), pk2(e[2].y, e[3].y),
                       pk2(e[4].y, e[5].y), pk2(e[6].y, e[7].y)};
    const int dA = 2 * d2, dB = dA + 1;
    *(u32x4*)(smem + V_OFF + dA * 128 + ((unsigned)(jc * 16) ^ ((unsigned)(dA & 7) << 4))) = wA;
    *(u32x4*)(smem + V_OFF + dB * 128 + ((unsigned)(jc * 16) ^ ((unsigned)(dB & 7) << 4))) = wB;

    const int r = rbase0 + prr;
    const int slot = r & 127;
    const unsigned swR = (unsigned)((slot & 7) << 4);
    const float* rp = k_head_r + (size_t)r * 4096 + bn * 64 + pdh * 32;
#pragma unroll
    for (int h = 0; h < 4; h++) {
      float4 b0 = *(const float4*)(rp + h * 8);
      float4 b1 = *(const float4*)(rp + h * 8 + 4);
      u32x4 ww = (u32x4){pk2(b0.x, b0.y), pk2(b0.z, b0.w), pk2(b1.x, b1.y), pk2(b1.z, b1.w)};
      *(u32x4*)(smem + KR_OFF + slot * 128 + ((unsigned)(pdh * 64 + h * 16) ^ swR)) = ww;
    }
  }

  // ---- per-lane Q fragments (plain bf16) + seg-dot partials ----
  const int qrow = i0 + 16 * w + lan16;
  const float* qp = q_head + (size_t)qrow * 4096 + bn * 64;
  S8U qa_h[2], qb_h[2];
  float e0p = 0.f, e1p = 0.f;
#pragma unroll
  for (int kc = 0; kc < 2; kc++) {
    const int d0 = kc * 32 + g * 8;
    float4 qv0 = *(const float4*)(qp + d0);
    float4 qv1 = *(const float4*)(qp + d0 + 4);
    float4 wb0 = *(const float4*)(r_w_bias + n * 64 + d0);
    float4 wb1 = *(const float4*)(r_w_bias + n * 64 + d0 + 4);
    float4 rb0 = *(const float4*)(r_r_bias + n * 64 + d0);
    float4 rb1 = *(const float4*)(r_r_bias + n * 64 + d0 + 4);
    float4 sb0 = *(const float4*)(r_s_bias + n * 64 + d0);
    float4 sb1 = *(const float4*)(r_s_bias + n * 64 + d0 + 4);
    float4 s00 = *(const float4*)(seg_embed + n * 64 + d0);
    float4 s01 = *(const float4*)(seg_embed + n * 64 + d0 + 4);
    float4 s10 = *(const float4*)(seg_embed + 1024 + n * 64 + d0);
    float4 s11 = *(const float4*)(seg_embed + 1024 + n * 64 + d0 + 4);
    qa_h[kc].u = (u32x4){pk2(qv0.x + wb0.x, qv0.y + wb0.y),
                         pk2(qv0.z + wb0.z, qv0.w + wb0.w),
                         pk2(qv1.x + wb1.x, qv1.y + wb1.y),
                         pk2(qv1.z + wb1.z, qv1.w + wb1.w)};
    qb_h[kc].u = (u32x4){pk2(qv0.x + rb0.x, qv0.y + rb0.y),
                         pk2(qv0.z + rb0.z, qv0.w + rb0.w),
                         pk2(qv1.x + rb1.x, qv1.y + rb1.y),
                         pk2(qv1.z + rb1.z, qv1.w + rb1.w)};
    float c0;
    c0 = qv0.x + sb0.x; e0p = fmaf(c0, s00.x, e0p); e1p = fmaf(c0, s10.x, e1p);
    c0 = qv0.y + sb0.y; e0p = fmaf(c0, s00.y, e0p); e1p = fmaf(c0, s10.y, e1p);
    c0 = qv0.z + sb0.z; e0p = fmaf(c0, s00.z, e0p); e1p = fmaf(c0, s10.z, e1p);
    c0 = qv0.w + sb0.w; e0p = fmaf(c0, s00.w, e0p); e1p = fmaf(c0, s10.w, e1p);
    c0 = qv1.x + sb1.x; e0p = fmaf(c0, s01.x, e0p); e1p = fmaf(c0, s11.x, e1p);
    c0 = qv1.y + sb1.y; e0p = fmaf(c0, s01.y, e0p); e1p = fmaf(c0, s11.y, e1p);
    c0 = qv1.z + sb1.z; e0p = fmaf(c0, s01.z, e0p); e1p = fmaf(c0, s11.z, e1p);
    c0 = qv1.w + sb1.w; e0p = fmaf(c0, s01.w, e0p); e1p = fmaf(c0, s11.w, e1p);
  }
  e0p += __shfl_xor(e0p, 16); e0p += __shfl_xor(e0p, 32);
  e1p += __shfl_xor(e1p, 16); e1p += __shfl_xor(e1p, 32);
  // UNSCALED eq values; folded into MFMA C-init as X = ef + (mask ? -8e30 : 0),
  // so sc = (QK + X + bd)*0.125 = (QK+bd)*0.125 + ef*0.125 + pen.
  float eqa0[4], eqa1[4];
#pragma unroll
  for (int r = 0; r < 4; r++) {
    eqa0[r] = __shfl(e0p, 4 * g + r);
    eqa1[r] = __shfl(e1p, 4 * g + r);
  }

  const unsigned swK = (unsigned)((lan16 & 7) << 4);
  float m_[4], l_[4];
  f32x4 accO[4];
#pragma unroll
  for (int r = 0; r < 4; r++) { m_[r] = -1e30f; l_[r] = 0.f; }
#pragma unroll
  for (int dt = 0; dt < 4; dt++) accO[dt] = (f32x4){0.f, 0.f, 0.f, 0.f};

  __syncthreads();

  for (int t = 0; t < 16; t++) {
    if (t > 0) {
      __syncthreads();
      if constexpr (MODE == 2) {
        const unsigned char* kt = kimg + (size_t)(bn * 16 + t) * 8192;
        *(u32x4*)(smem + K_OFF + tid * 32)      = *(const u32x4*)(kt + tid * 32);
        *(u32x4*)(smem + K_OFF + tid * 32 + 16) = *(const u32x4*)(kt + tid * 32 + 16);
        const unsigned char* vt = vimg + (size_t)(bn * 16 + t) * 8192;
        *(u32x4*)(smem + V_OFF + tid * 32)      = *(const u32x4*)(vt + tid * 32);
        *(u32x4*)(smem + V_OFF + tid * 32 + 16) = *(const u32x4*)(vt + tid * 32 + 16);
        const int rn = rbase0 + (t << 6) + 64 + jj;
        const int rcl = rn > 2047 ? 2047 : rn;
        const unsigned char* rs = krimg + ((size_t)bn * 2048 + rcl) * 128 + dblk * 32;
        unsigned char* rd = smem + KR_OFF + (rcl & 127) * 128 + dblk * 32;
        *(u32x4*)(rd)      = *(const u32x4*)(rs);
        *(u32x4*)(rd + 16) = *(const u32x4*)(rs + 16);
      } else {
        const int j0 = t << 6;
        const float* kp = k_head_h + (size_t)(j0 + jj) * 4096 + bn * 64 + dblk * 16;
        float4 a0 = *(const float4*)(kp);
        float4 a1 = *(const float4*)(kp + 4);
        float4 a2 = *(const float4*)(kp + 8);
        float4 a3 = *(const float4*)(kp + 12);
        const unsigned swJ = (unsigned)((jj & 7) << 4);
        u32x4 w0 = (u32x4){pk2(a0.x, a0.y), pk2(a0.z, a0.w), pk2(a1.x, a1.y), pk2(a1.z, a1.w)};
        u32x4 w1 = (u32x4){pk2(a2.x, a2.y), pk2(a2.z, a2.w), pk2(a3.x, a3.y), pk2(a3.z, a3.w)};
        *(u32x4*)(smem + K_OFF + jj * 128 + ((unsigned)(dblk * 32) ^ swJ)) = w0;
        *(u32x4*)(smem + K_OFF + jj * 128 + ((unsigned)(dblk * 32 + 16) ^ swJ)) = w1;

        const float* vp = v_head_h + (size_t)(j0 + jc * 8) * 4096 + bn * 64 + 2 * d2;
        float2 e[8];
#pragma unroll
        for (int q8 = 0; q8 < 8; q8++) e[q8] = *(const float2*)(vp + (size_t)q8 * 4096);
        u32x4 wA = (u32x4){pk2(e[0].x, e[1].x), pk2(e[2].x, e[3].x),
                           pk2(e[4].x, e[5].x), pk2(e[6].x, e[7].x)};
        u32x4 wB = (u32x4){pk2(e[0].y, e[1].y), pk2(e[2].y, e[3].y),
                           pk2(e[4].y, e[5].y), pk2(e[6].y, e[7].y)};
        const int dA = 2 * d2, dB = dA + 1;
        *(u32x4*)(smem + V_OFF + dA * 128 + ((unsigned)(jc * 16) ^ ((unsigned)(dA & 7) << 4))) = wA;
        *(u32x4*)(smem + V_OFF + dB * 128 + ((unsigned)(jc * 16) ^ ((unsigned)(dB & 7) << 4))) = wB;

        const int rn = rbase0 + (t << 6) + 64 + jj;
        const int rcl = rn > 2047 ? 2047 : rn;
        const int slotn = rn & 127;
        const unsigned swN = (unsigned)((slotn & 7) << 4);
        const float* rp = k_head_r + (size_t)rcl * 4096 + bn * 64 + dblk * 16;
        float4 b0 = *(const float4*)(rp);
        float4 b1 = *(const float4*)(rp + 4);
        float4 b2 = *(const float4*)(rp + 8);
        float4 b3 = *(const float4*)(rp + 12);
        u32x4 r0 = (u32x4){pk2(b0.x, b0.y), pk2(b0.z, b0.w), pk2(b1.x, b1.y), pk2(b1.z, b1.w)};
        u32x4 r1 = (u32x4){pk2(b2.x, b2.y), pk2(b2.z, b2.w), pk2(b3.x, b3.y), pk2(b3.z, b3.w)};
        *(u32x4*)(smem + KR_OFF + slotn * 128 + ((unsigned)(dblk * 32) ^ swN)) = r0;
        *(u32x4*)(smem + KR_OFF + slotn * 128 + ((unsigned)(dblk * 32 + 16) ^ swN)) = r1;
      }
      __syncthreads();
    }

    // ---- mask/seg decoded DIRECTLY into MFMA C-init (no separate T array) ----
    f32x4 acc[4];
    if constexpr (MODE >= 1) {
#pragma unroll
      for (int r = 0; r < 4; r++) {
        const int qr = i0 + 16 * w + 4 * g + r;
        const unsigned pv =
            *(const unsigned*)(pb + (((size_t)qr * 4 + b) * 16 + t) * 64 + lan16 * 4);
#pragma unroll
        for (int c = 0; c < 4; c++) {
          const unsigned byv = (pv >> (8 * c)) & 0xFFu;
          acc[c][r] = ((byv & 1u) ? eqa1[r] : eqa0[r]) + ((byv & 2u) ? -8e30f : 0.0f);
        }
      }
    } else {
      const int j0 = t << 6;
#pragma unroll
      for (int c = 0; c < 4; c++)
#pragma unroll
        for (int r = 0; r < 4; r++) {
          const int sidx = ((i0 + 16 * w + 4 * g + r) * 1024 + (j0 + 16 * c + lan16)) * 4 + b;
          const bool mk = attn_mask[sidx] != 0.0f;
          bool sv;
          if (segmode == 0)      sv = ((const int*)seg_mat)[sidx] != 0;
          else if (segmode == 1) sv = ((const float*)seg_mat)[sidx] != 0.0f;
          else                   sv = ((const unsigned char*)seg_mat)[sidx] != 0;
          acc[c][r] = (sv ? eqa1[r] : eqa0[r]) + (mk ? -8e30f : 0.0f);
        }
    }

    __builtin_amdgcn_s_setprio(1);
    // ---- ac = (q + r_w_bias) K^T  (accumulates on top of the X init) ----
#pragma unroll
    for (int c = 0; c < 4; c++) {
#pragma unroll
      for (int kc = 0; kc < 2; kc++) {
        S8U bf;
        bf.u = *(const u32x4*)(smem + K_OFF + (16 * c + lan16) * 128 +
                               ((unsigned)(kc * 64 + g * 16) ^ swK));
        acc[c] = MFMA16(qa_h[kc].s, bf.s, acc[c]);
      }
    }
    // ---- bd band kept IN REGISTERS (bda[5]); no LDS round-trip ----
    f32x4 bda[5];
#pragma unroll
    for (int tr = 0; tr < 5; tr++) {
      bda[tr] = (f32x4){0.f, 0.f, 0.f, 0.f};
      const int rowa = rbase0 + (t << 6) + 48 - 16 * w + 16 * tr + lan16;
      const int slot = rowa & 127;
      const unsigned swS = (unsigned)((slot & 7) << 4);
#pragma unroll
      for (int kc = 0; kc < 2; kc++) {
        S8U bf;
        bf.u = *(const u32x4*)(smem + KR_OFF + slot * 128 +
                               ((unsigned)(kc * 64 + g * 16) ^ swS));
        bda[tr] = MFMA16(qb_h[kc].s, bf.s, bda[tr]);
      }
    }
    __builtin_amdgcn_s_setprio(0);

    // ---- finalize scores + online softmax; BD gathered via in-group shuffles ----
    // Consumer (g,lan16,r) needs band pos bp = 16c + s, s = lan16-(4g+r)+15 in [0,30];
    // producer is SAME group g, SAME r: register bda[c + (s>=16)] of lane (s&15).
    float p[4][4];
#pragma unroll
    for (int r = 0; r < 4; r++) {
      const int qloc = 4 * g + r;
      const int s = lan16 - qloc + 15;
      const int lp = s & 15;
      const bool hi = s >= 16;
      float bs[5];
#pragma unroll
      for (int tr = 0; tr < 5; tr++) bs[tr] = __shfl(bda[tr][r], lp, 16);
      float sc[4];
#pragma unroll
      for (int c = 0; c < 4; c++) {
        const float bd = hi ? bs[c + 1] : bs[c];
        sc[c] = (acc[c][r] + bd) * 0.125f;
      }
      float mx = fmaxf(fmaxf(sc[0], sc[1]), fmaxf(sc[2], sc[3]));
      mx = fmaxf(mx, __shfl_xor(mx, 1));
      mx = fmaxf(mx, __shfl_xor(mx, 2));
      mx = fmaxf(mx, __shfl_xor(mx, 4));
      mx = fmaxf(mx, __shfl_xor(mx, 8));
      const float mn = fmaxf(m_[r], mx);
      const float f = __expf(m_[r] - mn);
      float sum = 0.f;
#pragma unroll
      for (int c = 0; c < 4; c++) { p[c][r] = __expf(sc[c] - mn); sum += p[c][r]; }
      sum += __shfl_xor(sum, 1);
      sum += __shfl_xor(sum, 2);
      sum += __shfl_xor(sum, 4);
      sum += __shfl_xor(sum, 8);
      l_[r] = l_[r] * f + sum;
      m_[r] = mn;
#pragma unroll
      for (int dt = 0; dt < 4; dt++) accO[dt][r] *= f;
    }
    // ---- write P (bf16, swizzled, stride 128) ----
#pragma unroll
    for (int c = 0; c < 4; c++)
#pragma unroll
      for (int r = 0; r < 4; r++) {
        const int row = 16 * w + 4 * g + r;
        const unsigned col2 = (unsigned)((16 * c + lan16) * 2);
        *(unsigned short*)(smem + P_OFF + row * 128 +
                           (col2 ^ (((unsigned)((4 * g + r) & 7)) << 4))) = f2bf(p[c][r]);
      }
    // ---- PV ----
    S8U pa[2];
#pragma unroll
    for (int kc = 0; kc < 2; kc++)
      pa[kc].u = *(const u32x4*)(smem + P_OFF + (16 * w + lan16) * 128 +
                                 ((unsigned)(kc * 64 + g * 16) ^ swK));
    __builtin_amdgcn_s_setprio(1);
#pragma unroll
    for (int dt = 0; dt < 4; dt++) {
      const int drow = 16 * dt + lan16;
      S8U v0, v1;
      v0.u = *(const u32x4*)(smem + V_OFF + drow * 128 + ((unsigned)(g * 16) ^ swK));
      v1.u = *(const u32x4*)(smem + V_OFF + drow * 128 + ((unsigned)(64 + g * 16) ^ swK));
      accO[dt] = MFMA16(pa[0].s, v0.s, accO[dt]);
      accO[dt] = MFMA16(pa[1].s, v1.s, accO[dt]);
    }
    __builtin_amdgcn_s_setprio(0);
  }

  // ---- epilogue ----
#pragma unroll
  for (int r = 0; r < 4; r++) {
    const float linv = 1.0f / l_[r];
    const int q = i0 + 16 * w + 4 * g + r;
    float* op = out + (size_t)q * 4096 + bn * 64 + lan16;
#pragma unroll
    for (int dt = 0; dt < 4; dt++) op[dt * 16] = accO[dt][r] * linv;
  }
}

extern "C" void kernel_launch(void* const* d_in, const int* in_sizes, int n_in,
                              void* d_out, int out_size, void* d_ws, size_t ws_size,
                              hipStream_t stream) {
  int* flags = reinterpret_cast<int*>(d_ws);
  unsigned char* wsb = reinterpret_cast<unsigned char*>(d_ws);
  unsigned char* pb    = wsb + 256;
  unsigned char* kimg  = pb + (size_t)4 * 1024 * 1024;
  unsigned char* vimg  = kimg + (size_t)8 * 1024 * 1024;
  unsigned char* krimg = vimg + (size_t)8 * 1024 * 1024;
  const size_t need1 = (size_t)4 * 1024 * 1024 + 256;
  const size_t need2 = need1 + (size_t)32 * 1024 * 1024;

  hipLaunchKernelGGL(detect_kernel, dim3(1), dim3(64), 0, stream,
                     (const unsigned*)d_in[9], flags);
  if (ws_size >= need2) {
    hipLaunchKernelGGL(pack_kernel, dim3(4096), dim3(256), 0, stream,
                       (const float*)d_in[8], (const void*)d_in[9], flags, pb);
    hipLaunchKernelGGL(prepack_kernel, dim3(3072), dim3(256), 0, stream,
                       (const float*)d_in[1], (const float*)d_in[2], (const float*)d_in[3],
                       kimg, vimg, krimg);
    hipLaunchKernelGGL((attn_mfma<2>), dim3(1024), dim3(256), 0, stream,
                       (const float*)d_in[0], (const float*)d_in[1], (const float*)d_in[2],
                       (const float*)d_in[3], (const float*)d_in[4], (const float*)d_in[5],
                       (const float*)d_in[6], (const float*)d_in[7], (const float*)d_in[8],
                       (const void*)d_in[9], pb, kimg, vimg, krimg, (float*)d_out, flags);
  } else if (ws_size >= need1) {
    hipLaunchKernelGGL(pack_kernel, dim3(4096), dim3(256), 0, stream,
                       (const float*)d_in[8], (const void*)d_in[9], flags, pb);
    hipLaunchKernelGGL((attn_mfma<1>), dim3(1024), dim3(256), 0, stream,
                       (const float*)d_in[0], (const float*)d_in[1], (const float*)d_in[2],
                       (const float*)d_in[3], (const float*)d_in[4], (const float*)d_in[5],
                       (const float*)d_in[6], (const float*)d_in[7], (const float*)d_in[8],
                       (const void*)d_in[9], pb, pb, pb, pb, (float*)d_out, flags);
  } else {
    hipLaunchKernelGGL((attn_mfma<0>), dim3(1024), dim3(256), 0, stream,
                       (const float*)d_in[0], (const float*)d_in[1], (const float*)d_in[2],
                       (const float*)d_in[3], (const float*)d_in[4], (const float*)d_in[5],
                       (const float*)d_in[6], (const float*)d_in[7], (const float*)d_in[8],
                       (const void*)d_in[9], pb, pb, pb, pb, (float*)d_out, flags);
  }
}

// Round 19
// 127.699 us; speedup vs baseline: 1.0613x; 1.0613x over previous
//
#include <hip/hip_runtime.h>

typedef __attribute__((ext_vector_type(8))) short short8;
typedef __attribute__((ext_vector_type(4))) float f32x4;
typedef __attribute__((ext_vector_type(4))) unsigned int u32x4;

// ---- LDS layout: exactly 40 KB ----
#define K_OFF   0              // 64 rows x 128 B (K tile, bf16, swizzled)
#define KR_OFF  8192           // 128 slots x 128 B (k_r circular band)
#define V_OFF   24576          // 64 d-rows x 128 B (V transposed)
#define P_OFF   32768          // 64 rows x 128 B (P bf16, swizzled)
#define SMEM_SZ 40960

union S8U { u32x4 u; short8 s; };

// Manual RNE bf16 pack (PROVEN r3-r18). NOT pk2-via-cvt (r6 fail: pair order).
__device__ __forceinline__ unsigned short f2bf(float x) {
  unsigned u = __float_as_uint(x);
  return (unsigned short)((u + 0x7FFFu + ((u >> 16) & 1u)) >> 16);
}
__device__ __forceinline__ unsigned pk2(float a, float b) {
  return (unsigned)f2bf(a) | ((unsigned)f2bf(b) << 16);
}

// seg_mat dtype probe: flags[0] = 0:int32  1:f32  2:byte/bool
__global__ void detect_kernel(const unsigned* __restrict__ segw, int* __restrict__ flags) {
  if (threadIdx.x >= 64) return;
  int a = 0, c = 0;
  for (int i = threadIdx.x; i < 1024; i += 64) {
    unsigned v = segw[i];
    if (v > 1u) a++;
    if (v != 0u && v != 0x3F800000u) c++;
  }
  for (int m = 1; m < 64; m <<= 1) { a += __shfl_xor(a, m); c += __shfl_xor(c, m); }
  if (threadIdx.x == 0) flags[0] = (a == 0) ? 0 : ((c == 0) ? 1 : 2);
}

// pb[(((q*4+b)*16 + t)*64 + lan16*4 + c] = (mask!=0)<<1 | (seg!=0)
__global__ __launch_bounds__(256) void
pack_kernel(const float* __restrict__ attn_mask, const void* __restrict__ seg_mat,
            const int* __restrict__ flags, unsigned char* __restrict__ pb) {
  const int segmode = flags[0];
  const int idx = blockIdx.x * 256 + threadIdx.x;
  const int q = idx >> 10, j = idx & 1023;
  const int tt = j >> 6, cc = (j >> 4) & 3, ll = j & 15;
  const float4 m4 = *(const float4*)(attn_mask + (size_t)idx * 4);
  unsigned sm[4];
  if (segmode == 2) {
    const unsigned char* sp = (const unsigned char*)seg_mat + (size_t)idx * 4;
    sm[0] = sp[0]; sm[1] = sp[1]; sm[2] = sp[2]; sm[3] = sp[3];
  } else {
    const unsigned* sp = (const unsigned*)seg_mat + (size_t)idx * 4;
    sm[0] = sp[0]; sm[1] = sp[1]; sm[2] = sp[2]; sm[3] = sp[3];
  }
  const float mm[4] = {m4.x, m4.y, m4.z, m4.w};
#pragma unroll
  for (int b = 0; b < 4; b++)
    pb[(((size_t)q * 4 + b) * 16 + tt) * 64 + ll * 4 + cc] =
        (unsigned char)(((mm[b] != 0.f) ? 2u : 0u) | ((sm[b] != 0u) ? 1u : 0u));
}

// One-time f32->bf16 image prepack in exact main-kernel LDS byte layout (PROVEN r9).
__global__ __launch_bounds__(256) void
prepack_kernel(const float* __restrict__ k_head_h, const float* __restrict__ v_head_h,
               const float* __restrict__ k_head_r,
               unsigned char* __restrict__ kimg, unsigned char* __restrict__ vimg,
               unsigned char* __restrict__ krimg) {
  __shared__ float vst[64 * 68];
  const int blk = blockIdx.x, tid = threadIdx.x;
  if (blk < 1024) {
    const int bn = blk >> 4, t = blk & 15;
    const int jj = tid >> 2, dblk = tid & 3;
    const float* kp = k_head_h + (size_t)(t * 64 + jj) * 4096 + bn * 64 + dblk * 16;
    float4 a0 = *(const float4*)(kp);
    float4 a1 = *(const float4*)(kp + 4);
    float4 a2 = *(const float4*)(kp + 8);
    float4 a3 = *(const float4*)(kp + 12);
    const unsigned swJ = (unsigned)((jj & 7) << 4);
    u32x4 w0 = (u32x4){pk2(a0.x, a0.y), pk2(a0.z, a0.w), pk2(a1.x, a1.y), pk2(a1.z, a1.w)};
    u32x4 w1 = (u32x4){pk2(a2.x, a2.y), pk2(a2.z, a2.w), pk2(a3.x, a3.y), pk2(a3.z, a3.w)};
    unsigned char* dst = kimg + (size_t)blk * 8192 + jj * 128;
    *(u32x4*)(dst + ((unsigned)(dblk * 32) ^ swJ)) = w0;
    *(u32x4*)(dst + ((unsigned)(dblk * 32 + 16) ^ swJ)) = w1;
  } else if (blk < 2048) {
    const int b2 = blk - 1024;
    const int bn = b2 >> 4, t = b2 & 15;
    const int jj = tid >> 2, dblk = tid & 3;
    const float* vp = v_head_h + (size_t)(t * 64 + jj) * 4096 + bn * 64 + dblk * 16;
    float4 a0 = *(const float4*)(vp);
    float4 a1 = *(const float4*)(vp + 4);
    float4 a2 = *(const float4*)(vp + 8);
    float4 a3 = *(const float4*)(vp + 12);
    float* vr = &vst[jj * 68 + dblk * 16];
    *(float4*)(vr) = a0; *(float4*)(vr + 4) = a1;
    *(float4*)(vr + 8) = a2; *(float4*)(vr + 12) = a3;
    __syncthreads();
    const int d2 = tid & 31, jc = tid >> 5;
    float2 e[8];
#pragma unroll
    for (int q8 = 0; q8 < 8; q8++)
      e[q8] = *(const float2*)(&vst[(jc * 8 + q8) * 68 + 2 * d2]);
    u32x4 wA = (u32x4){pk2(e[0].x, e[1].x), pk2(e[2].x, e[3].x),
                       pk2(e[4].x, e[5].x), pk2(e[6].x, e[7].x)};
    u32x4 wB = (u32x4){pk2(e[0].y, e[1].y), pk2(e[2].y, e[3].y),
                       pk2(e[4].y, e[5].y), pk2(e[6].y, e[7].y)};
    const int dA = 2 * d2, dB = dA + 1;
    unsigned char* dst = vimg + (size_t)b2 * 8192;
    *(u32x4*)(dst + dA * 128 + ((unsigned)(jc * 16) ^ ((unsigned)(dA & 7) << 4))) = wA;
    *(u32x4*)(dst + dB * 128 + ((unsigned)(jc * 16) ^ ((unsigned)(dB & 7) << 4))) = wB;
  } else {
    const int b3 = blk - 2048;
    const int bn = b3 >> 4, rseg = b3 & 15;
    const int r = rseg * 128 + (tid >> 1), dh = tid & 1;
    const unsigned sw = (unsigned)((r & 7) << 4);
    const float* rp = k_head_r + (size_t)r * 4096 + bn * 64 + dh * 32;
    unsigned char* dst = krimg + ((size_t)bn * 2048 + r) * 128;
#pragma unroll
    for (int h = 0; h < 4; h++) {
      float4 b0 = *(const float4*)(rp + h * 8);
      float4 b1 = *(const float4*)(rp + h * 8 + 4);
      u32x4 ww = (u32x4){pk2(b0.x, b0.y), pk2(b0.z, b0.w), pk2(b1.x, b1.y), pk2(b1.z, b1.w)};
      *(u32x4*)(dst + ((unsigned)(dh * 64 + h * 16) ^ sw)) = ww;
    }
  }
}

#define MFMA16(A, B, C) __builtin_amdgcn_mfma_f32_16x16x32_bf16((A), (B), (C), 0, 0, 0)

// MODE: 0 = naive, 1 = pb, 2 = pb + bf16 images
template<int MODE>
__global__ __launch_bounds__(256, 4) void   // (256,4): pin arch VGPR to 64 (r7-observed); natural ~66 after eqa-shave
attn_mfma(const float* __restrict__ q_head, const float* __restrict__ k_head_h,
          const float* __restrict__ v_head_h, const float* __restrict__ k_head_r,
          const float* __restrict__ seg_embed, const float* __restrict__ r_w_bias,
          const float* __restrict__ r_r_bias, const float* __restrict__ r_s_bias,
          const float* __restrict__ attn_mask, const void* __restrict__ seg_mat,
          const unsigned char* __restrict__ pb,
          const unsigned char* __restrict__ kimg, const unsigned char* __restrict__ vimg,
          const unsigned char* __restrict__ krimg,
          float* __restrict__ out, const int* __restrict__ flags) {
  __shared__ __attribute__((aligned(128))) unsigned char smem[SMEM_SZ];
  const int segmode = flags[0];
  const int tid = threadIdx.x;
  const int w = tid >> 6, l = tid & 63;
  const int g = l >> 4, lan16 = l & 15;
  const int orig = blockIdx.x;
  const int wg = ((orig & 7) << 7) | (orig >> 3);
  const int i0 = (wg & 15) << 6;
  const int bn = wg >> 4, b = bn >> 4, n = bn & 15;
  const int rbase0 = 961 - i0;

  const int jj = tid >> 2, dblk = tid & 3;
  const int d2 = tid & 31, jc = tid >> 5;
  const int prr = tid >> 1, pdh = tid & 1;

  // ---- prologue: stage tile 0 ----
  if constexpr (MODE == 2) {
    const unsigned char* kt = kimg + (size_t)(bn * 16) * 8192;
    *(u32x4*)(smem + K_OFF + tid * 32)      = *(const u32x4*)(kt + tid * 32);
    *(u32x4*)(smem + K_OFF + tid * 32 + 16) = *(const u32x4*)(kt + tid * 32 + 16);
    const unsigned char* vt = vimg + (size_t)(bn * 16) * 8192;
    *(u32x4*)(smem + V_OFF + tid * 32)      = *(const u32x4*)(vt + tid * 32);
    *(u32x4*)(smem + V_OFF + tid * 32 + 16) = *(const u32x4*)(vt + tid * 32 + 16);
    const int r = rbase0 + prr;
    const unsigned char* rs = krimg + ((size_t)bn * 2048 + r) * 128 + pdh * 64;
    unsigned char* rd = smem + KR_OFF + (r & 127) * 128 + pdh * 64;   // slot&7==r&7: identity
    *(u32x4*)(rd)      = *(const u32x4*)(rs);
    *(u32x4*)(rd + 16) = *(const u32x4*)(rs + 16);
    *(u32x4*)(rd + 32) = *(const u32x4*)(rs + 32);
    *(u32x4*)(rd + 48) = *(const u32x4*)(rs + 48);
  } else {
    const float* kp = k_head_h + (size_t)jj * 4096 + bn * 64 + dblk * 16;
    float4 a0 = *(const float4*)(kp);
    float4 a1 = *(const float4*)(kp + 4);
    float4 a2 = *(const float4*)(kp + 8);
    float4 a3 = *(const float4*)(kp + 12);
    const unsigned swJ = (unsigned)((jj & 7) << 4);
    u32x4 w0 = (u32x4){pk2(a0.x, a0.y), pk2(a0.z, a0.w), pk2(a1.x, a1.y), pk2(a1.z, a1.w)};
    u32x4 w1 = (u32x4){pk2(a2.x, a2.y), pk2(a2.z, a2.w), pk2(a3.x, a3.y), pk2(a3.z, a3.w)};
    *(u32x4*)(smem + K_OFF + jj * 128 + ((unsigned)(dblk * 32) ^ swJ)) = w0;
    *(u32x4*)(smem + K_OFF + jj * 128 + ((unsigned)(dblk * 32 + 16) ^ swJ)) = w1;

    const float* vp = v_head_h + (size_t)(jc * 8) * 4096 + bn * 64 + 2 * d2;
    float2 e[8];
#pragma unroll
    for (int q8 = 0; q8 < 8; q8++) e[q8] = *(const float2*)(vp + (size_t)q8 * 4096);
    u32x4 wA = (u32x4){pk2(e[0].x, e[1].x), pk2(e[2].x, e[3].x),
                       pk2(e[4].x, e[5].x), pk2(e[6].x, e[7].x)};
    u32x4 wB = (u32x4){pk2(e[0].y, e[1].y), pk2(e[2].y, e[3].y),
                       pk2(e[4].y, e[5].y), pk2(e[6].y, e[7].y)};
    const int dA = 2 * d2, dB = dA + 1;
    *(u32x4*)(smem + V_OFF + dA * 128 + ((unsigned)(jc * 16) ^ ((unsigned)(dA & 7) << 4))) = wA;
    *(u32x4*)(smem + V_OFF + dB * 128 + ((unsigned)(jc * 16) ^ ((unsigned)(dB & 7) << 4))) = wB;

    const int r = rbase0 + prr;
    const int slot = r & 127;
    const unsigned swR = (unsigned)((slot & 7) << 4);
    const float* rp = k_head_r + (size_t)r * 4096 + bn * 64 + pdh * 32;
#pragma unroll
    for (int h = 0; h < 4; h++) {
      float4 b0 = *(const float4*)(rp + h * 8);
      float4 b1 = *(const float4*)(rp + h * 8 + 4);
      u32x4 ww = (u32x4){pk2(b0.x, b0.y), pk2(b0.z, b0.w), pk2(b1.x, b1.y), pk2(b1.z, b1.w)};
      *(u32x4*)(smem + KR_OFF + slot * 128 + ((unsigned)(pdh * 64 + h * 16) ^ swR)) = ww;
    }
  }

  // ---- per-lane Q fragments (plain bf16) + seg-dot partials ----
  const int qrow = i0 + 16 * w + lan16;
  const float* qp = q_head + (size_t)qrow * 4096 + bn * 64;
  S8U qa_h[2], qb_h[2];
  float e0p = 0.f, e1p = 0.f;
#pragma unroll
  for (int kc = 0; kc < 2; kc++) {
    const int d0 = kc * 32 + g * 8;
    float4 qv0 = *(const float4*)(qp + d0);
    float4 qv1 = *(const float4*)(qp + d0 + 4);
    float4 wb0 = *(const float4*)(r_w_bias + n * 64 + d0);
    float4 wb1 = *(const float4*)(r_w_bias + n * 64 + d0 + 4);
    float4 rb0 = *(const float4*)(r_r_bias + n * 64 + d0);
    float4 rb1 = *(const float4*)(r_r_bias + n * 64 + d0 + 4);
    float4 sb0 = *(const float4*)(r_s_bias + n * 64 + d0);
    float4 sb1 = *(const float4*)(r_s_bias + n * 64 + d0 + 4);
    float4 s00 = *(const float4*)(seg_embed + n * 64 + d0);
    float4 s01 = *(const float4*)(seg_embed + n * 64 + d0 + 4);
    float4 s10 = *(const float4*)(seg_embed + 1024 + n * 64 + d0);
    float4 s11 = *(const float4*)(seg_embed + 1024 + n * 64 + d0 + 4);
    qa_h[kc].u = (u32x4){pk2(qv0.x + wb0.x, qv0.y + wb0.y),
                         pk2(qv0.z + wb0.z, qv0.w + wb0.w),
                         pk2(qv1.x + wb1.x, qv1.y + wb1.y),
                         pk2(qv1.z + wb1.z, qv1.w + wb1.w)};
    qb_h[kc].u = (u32x4){pk2(qv0.x + rb0.x, qv0.y + rb0.y),
                         pk2(qv0.z + rb0.z, qv0.w + rb0.w),
                         pk2(qv1.x + rb1.x, qv1.y + rb1.y),
                         pk2(qv1.z + rb1.z, qv1.w + rb1.w)};
    float c0;
    c0 = qv0.x + sb0.x; e0p = fmaf(c0, s00.x, e0p); e1p = fmaf(c0, s10.x, e1p);
    c0 = qv0.y + sb0.y; e0p = fmaf(c0, s00.y, e0p); e1p = fmaf(c0, s10.y, e1p);
    c0 = qv0.z + sb0.z; e0p = fmaf(c0, s00.z, e0p); e1p = fmaf(c0, s10.z, e1p);
    c0 = qv0.w + sb0.w; e0p = fmaf(c0, s00.w, e0p); e1p = fmaf(c0, s10.w, e1p);
    c0 = qv1.x + sb1.x; e0p = fmaf(c0, s01.x, e0p); e1p = fmaf(c0, s11.x, e1p);
    c0 = qv1.y + sb1.y; e0p = fmaf(c0, s01.y, e0p); e1p = fmaf(c0, s11.y, e1p);
    c0 = qv1.z + sb1.z; e0p = fmaf(c0, s01.z, e0p); e1p = fmaf(c0, s11.z, e1p);
    c0 = qv1.w + sb1.w; e0p = fmaf(c0, s01.w, e0p); e1p = fmaf(c0, s11.w, e1p);
  }
  e0p += __shfl_xor(e0p, 16); e0p += __shfl_xor(e0p, 32);
  e1p += __shfl_xor(e1p, 16); e1p += __shfl_xor(e1p, 32);
  // NOTE: no persistent eqa arrays — e0p/e1p (2 regs) shfl'd at decode point.
  // Folded into MFMA C-init as X = ef + (mask ? -8e30 : 0);
  // sc = (QK + X + bd)*0.125 = (QK+bd)*0.125 + ef*0.125 + pen.

  const unsigned swK = (unsigned)((lan16 & 7) << 4);
  float m_[4], l_[4];
  f32x4 accO[4];
#pragma unroll
  for (int r = 0; r < 4; r++) { m_[r] = -1e30f; l_[r] = 0.f; }
#pragma unroll
  for (int dt = 0; dt < 4; dt++) accO[dt] = (f32x4){0.f, 0.f, 0.f, 0.f};

  __syncthreads();

  for (int t = 0; t < 16; t++) {
    if (t > 0) {
      __syncthreads();
      if constexpr (MODE == 2) {
        const unsigned char* kt = kimg + (size_t)(bn * 16 + t) * 8192;
        *(u32x4*)(smem + K_OFF + tid * 32)      = *(const u32x4*)(kt + tid * 32);
        *(u32x4*)(smem + K_OFF + tid * 32 + 16) = *(const u32x4*)(kt + tid * 32 + 16);
        const unsigned char* vt = vimg + (size_t)(bn * 16 + t) * 8192;
        *(u32x4*)(smem + V_OFF + tid * 32)      = *(const u32x4*)(vt + tid * 32);
        *(u32x4*)(smem + V_OFF + tid * 32 + 16) = *(const u32x4*)(vt + tid * 32 + 16);
        const int rn = rbase0 + (t << 6) + 64 + jj;
        const int rcl = rn > 2047 ? 2047 : rn;
        const unsigned char* rs = krimg + ((size_t)bn * 2048 + rcl) * 128 + dblk * 32;
        unsigned char* rd = smem + KR_OFF + (rcl & 127) * 128 + dblk * 32;
        *(u32x4*)(rd)      = *(const u32x4*)(rs);
        *(u32x4*)(rd + 16) = *(const u32x4*)(rs + 16);
      } else {
        const int j0 = t << 6;
        const float* kp = k_head_h + (size_t)(j0 + jj) * 4096 + bn * 64 + dblk * 16;
        float4 a0 = *(const float4*)(kp);
        float4 a1 = *(const float4*)(kp + 4);
        float4 a2 = *(const float4*)(kp + 8);
        float4 a3 = *(const float4*)(kp + 12);
        const unsigned swJ = (unsigned)((jj & 7) << 4);
        u32x4 w0 = (u32x4){pk2(a0.x, a0.y), pk2(a0.z, a0.w), pk2(a1.x, a1.y), pk2(a1.z, a1.w)};
        u32x4 w1 = (u32x4){pk2(a2.x, a2.y), pk2(a2.z, a2.w), pk2(a3.x, a3.y), pk2(a3.z, a3.w)};
        *(u32x4*)(smem + K_OFF + jj * 128 + ((unsigned)(dblk * 32) ^ swJ)) = w0;
        *(u32x4*)(smem + K_OFF + jj * 128 + ((unsigned)(dblk * 32 + 16) ^ swJ)) = w1;

        const float* vp = v_head_h + (size_t)(j0 + jc * 8) * 4096 + bn * 64 + 2 * d2;
        float2 e[8];
#pragma unroll
        for (int q8 = 0; q8 < 8; q8++) e[q8] = *(const float2*)(vp + (size_t)q8 * 4096);
        u32x4 wA = (u32x4){pk2(e[0].x, e[1].x), pk2(e[2].x, e[3].x),
                           pk2(e[4].x, e[5].x), pk2(e[6].x, e[7].x)};
        u32x4 wB = (u32x4){pk2(e[0].y, e[1].y), pk2(e[2].y, e[3].y),
                           pk2(e[4].y, e[5].y), pk2(e[6].y, e[7].y)};
        const int dA = 2 * d2, dB = dA + 1;
        *(u32x4*)(smem + V_OFF + dA * 128 + ((unsigned)(jc * 16) ^ ((unsigned)(dA & 7) << 4))) = wA;
        *(u32x4*)(smem + V_OFF + dB * 128 + ((unsigned)(jc * 16) ^ ((unsigned)(dB & 7) << 4))) = wB;

        const int rn = rbase0 + (t << 6) + 64 + jj;
        const int rcl = rn > 2047 ? 2047 : rn;
        const int slotn = rn & 127;
        const unsigned swN = (unsigned)((slotn & 7) << 4);
        const float* rp = k_head_r + (size_t)rcl * 4096 + bn * 64 + dblk * 16;
        float4 b0 = *(const float4*)(rp);
        float4 b1 = *(const float4*)(rp + 4);
        float4 b2 = *(const float4*)(rp + 8);
        float4 b3 = *(const float4*)(rp + 12);
        u32x4 r0 = (u32x4){pk2(b0.x, b0.y), pk2(b0.z, b0.w), pk2(b1.x, b1.y), pk2(b1.z, b1.w)};
        u32x4 r1 = (u32x4){pk2(b2.x, b2.y), pk2(b2.z, b2.w), pk2(b3.x, b3.y), pk2(b3.z, b3.w)};
        *(u32x4*)(smem + KR_OFF + slotn * 128 + ((unsigned)(dblk * 32) ^ swN)) = r0;
        *(u32x4*)(smem + KR_OFF + slotn * 128 + ((unsigned)(dblk * 32 + 16) ^ swN)) = r1;
      }
      __syncthreads();
    }

    // ---- mask/seg decoded DIRECTLY into MFMA C-init; eq via shfl at use ----
    f32x4 acc[4];
    if constexpr (MODE >= 1) {
#pragma unroll
      for (int r = 0; r < 4; r++) {
        const float ea0 = __shfl(e0p, 4 * g + r);
        const float ea1 = __shfl(e1p, 4 * g + r);
        const int qr = i0 + 16 * w + 4 * g + r;
        const unsigned pv =
            *(const unsigned*)(pb + (((size_t)qr * 4 + b) * 16 + t) * 64 + lan16 * 4);
#pragma unroll
        for (int c = 0; c < 4; c++) {
          const unsigned byv = (pv >> (8 * c)) & 0xFFu;
          acc[c][r] = ((byv & 1u) ? ea1 : ea0) + ((byv & 2u) ? -8e30f : 0.0f);
        }
      }
    } else {
      const int j0 = t << 6;
#pragma unroll
      for (int r = 0; r < 4; r++) {
        const float ea0 = __shfl(e0p, 4 * g + r);
        const float ea1 = __shfl(e1p, 4 * g + r);
#pragma unroll
        for (int c = 0; c < 4; c++) {
          const int sidx = ((i0 + 16 * w + 4 * g + r) * 1024 + (j0 + 16 * c + lan16)) * 4 + b;
          const bool mk = attn_mask[sidx] != 0.0f;
          bool sv;
          if (segmode == 0)      sv = ((const int*)seg_mat)[sidx] != 0;
          else if (segmode == 1) sv = ((const float*)seg_mat)[sidx] != 0.0f;
          else                   sv = ((const unsigned char*)seg_mat)[sidx] != 0;
          acc[c][r] = (sv ? ea1 : ea0) + (mk ? -8e30f : 0.0f);
        }
      }
    }

    __builtin_amdgcn_s_setprio(1);
    // ---- ac = (q + r_w_bias) K^T  (accumulates on top of the X init) ----
#pragma unroll
    for (int c = 0; c < 4; c++) {
#pragma unroll
      for (int kc = 0; kc < 2; kc++) {
        S8U bf;
        bf.u = *(const u32x4*)(smem + K_OFF + (16 * c + lan16) * 128 +
                               ((unsigned)(kc * 64 + g * 16) ^ swK));
        acc[c] = MFMA16(qa_h[kc].s, bf.s, acc[c]);
      }
    }
    // ---- bd band kept IN REGISTERS (bda[5]); no LDS round-trip ----
    f32x4 bda[5];
#pragma unroll
    for (int tr = 0; tr < 5; tr++) {
      bda[tr] = (f32x4){0.f, 0.f, 0.f, 0.f};
      const int rowa = rbase0 + (t << 6) + 48 - 16 * w + 16 * tr + lan16;
      const int slot = rowa & 127;
      const unsigned swS = (unsigned)((slot & 7) << 4);
#pragma unroll
      for (int kc = 0; kc < 2; kc++) {
        S8U bf;
        bf.u = *(const u32x4*)(smem + KR_OFF + slot * 128 +
                               ((unsigned)(kc * 64 + g * 16) ^ swS));
        bda[tr] = MFMA16(qb_h[kc].s, bf.s, bda[tr]);
      }
    }
    __builtin_amdgcn_s_setprio(0);

    // ---- finalize scores + online softmax; BD gathered via in-group shuffles ----
    // Consumer (g,lan16,r) needs band pos bp = 16c + s, s = lan16-(4g+r)+15 in [0,30];
    // producer is SAME group g, SAME r: register bda[c + (s>=16)] of lane (s&15).
    float p[4][4];
#pragma unroll
    for (int r = 0; r < 4; r++) {
      const int qloc = 4 * g + r;
      const int s = lan16 - qloc + 15;
      const int lp = s & 15;
      const bool hi = s >= 16;
      float bs[5];
#pragma unroll
      for (int tr = 0; tr < 5; tr++) bs[tr] = __shfl(bda[tr][r], lp, 16);
      float sc[4];
#pragma unroll
      for (int c = 0; c < 4; c++) {
        const float bd = hi ? bs[c + 1] : bs[c];
        sc[c] = (acc[c][r] + bd) * 0.125f;
      }
      float mx = fmaxf(fmaxf(sc[0], sc[1]), fmaxf(sc[2], sc[3]));
      mx = fmaxf(mx, __shfl_xor(mx, 1));
      mx = fmaxf(mx, __shfl_xor(mx, 2));
      mx = fmaxf(mx, __shfl_xor(mx, 4));
      mx = fmaxf(mx, __shfl_xor(mx, 8));
      const float mn = fmaxf(m_[r], mx);
      const float f = __expf(m_[r] - mn);
      float sum = 0.f;
#pragma unroll
      for (int c = 0; c < 4; c++) { p[c][r] = __expf(sc[c] - mn); sum += p[c][r]; }
      sum += __shfl_xor(sum, 1);
      sum += __shfl_xor(sum, 2);
      sum += __shfl_xor(sum, 4);
      sum += __shfl_xor(sum, 8);
      l_[r] = l_[r] * f + sum;
      m_[r] = mn;
#pragma unroll
      for (int dt = 0; dt < 4; dt++) accO[dt][r] *= f;
    }
    // ---- write P (bf16, swizzled, stride 128) ----
#pragma unroll
    for (int c = 0; c < 4; c++)
#pragma unroll
      for (int r = 0; r < 4; r++) {
        const int row = 16 * w + 4 * g + r;
        const unsigned col2 = (unsigned)((16 * c + lan16) * 2);
        *(unsigned short*)(smem + P_OFF + row * 128 +
                           (col2 ^ (((unsigned)((4 * g + r) & 7)) << 4))) = f2bf(p[c][r]);
      }
    // ---- PV ----
    S8U pa[2];
#pragma unroll
    for (int kc = 0; kc < 2; kc++)
      pa[kc].u = *(const u32x4*)(smem + P_OFF + (16 * w + lan16) * 128 +
                                 ((unsigned)(kc * 64 + g * 16) ^ swK));
    __builtin_amdgcn_s_setprio(1);
#pragma unroll
    for (int dt = 0; dt < 4; dt++) {
      const int drow = 16 * dt + lan16;
      S8U v0, v1;
      v0.u = *(const u32x4*)(smem + V_OFF + drow * 128 + ((unsigned)(g * 16) ^ swK));
      v1.u = *(const u32x4*)(smem + V_OFF + drow * 128 + ((unsigned)(64 + g * 16) ^ swK));
      accO[dt] = MFMA16(pa[0].s, v0.s, accO[dt]);
      accO[dt] = MFMA16(pa[1].s, v1.s, accO[dt]);
    }
    __builtin_amdgcn_s_setprio(0);
  }

  // ---- epilogue ----
#pragma unroll
  for (int r = 0; r < 4; r++) {
    const float linv = 1.0f / l_[r];
    const int q = i0 + 16 * w + 4 * g + r;
    float* op = out + (size_t)q * 4096 + bn * 64 + lan16;
#pragma unroll
    for (int dt = 0; dt < 4; dt++) op[dt * 16] = accO[dt][r] * linv;
  }
}

extern "C" void kernel_launch(void* const* d_in, const int* in_sizes, int n_in,
                              void* d_out, int out_size, void* d_ws, size_t ws_size,
                              hipStream_t stream) {
  int* flags = reinterpret_cast<int*>(d_ws);
  unsigned char* wsb = reinterpret_cast<unsigned char*>(d_ws);
  unsigned char* pb    = wsb + 256;
  unsigned char* kimg  = pb + (size_t)4 * 1024 * 1024;
  unsigned char* vimg  = kimg + (size_t)8 * 1024 * 1024;
  unsigned char* krimg = vimg + (size_t)8 * 1024 * 1024;
  const size_t need1 = (size_t)4 * 1024 * 1024 + 256;
  const size_t need2 = need1 + (size_t)32 * 1024 * 1024;

  hipLaunchKernelGGL(detect_kernel, dim3(1), dim3(64), 0, stream,
                     (const unsigned*)d_in[9], flags);
  if (ws_size >= need2) {
    hipLaunchKernelGGL(pack_kernel, dim3(4096), dim3(256), 0, stream,
                       (const float*)d_in[8], (const void*)d_in[9], flags, pb);
    hipLaunchKernelGGL(prepack_kernel, dim3(3072), dim3(256), 0, stream,
                       (const float*)d_in[1], (const float*)d_in[2], (const float*)d_in[3],
                       kimg, vimg, krimg);
    hipLaunchKernelGGL((attn_mfma<2>), dim3(1024), dim3(256), 0, stream,
                       (const float*)d_in[0], (const float*)d_in[1], (const float*)d_in[2],
                       (const float*)d_in[3], (const float*)d_in[4], (const float*)d_in[5],
                       (const float*)d_in[6], (const float*)d_in[7], (const float*)d_in[8],
                       (const void*)d_in[9], pb, kimg, vimg, krimg, (float*)d_out, flags);
  } else if (ws_size >= need1) {
    hipLaunchKernelGGL(pack_kernel, dim3(4096), dim3(256), 0, stream,
                       (const float*)d_in[8], (const void*)d_in[9], flags, pb);
    hipLaunchKernelGGL((attn_mfma<1>), dim3(1024), dim3(256), 0, stream,
                       (const float*)d_in[0], (const float*)d_in[1], (const float*)d_in[2],
                       (const float*)d_in[3], (const float*)d_in[4], (const float*)d_in[5],
                       (const float*)d_in[6], (const float*)d_in[7], (const float*)d_in[8],
                       (const void*)d_in[9], pb, pb, pb, pb, (float*)d_out, flags);
  } else {
    hipLaunchKernelGGL((attn_mfma<0>), dim3(1024), dim3(256), 0, stream,
                       (const float*)d_in[0], (const float*)d_in[1], (const float*)d_in[2],
                       (const float*)d_in[3], (const float*)d_in[4], (const float*)d_in[5],
                       (const float*)d_in[6], (const float*)d_in[7], (const float*)d_in[8],
                       (const void*)d_in[9], pb, pb, pb, pb, (float*)d_out, flags);
  }
}